// Round 1
// baseline (312.964 us; speedup 1.0000x reference)
//
#include <hip/hip_runtime.h>
#include <math.h>

#define J 17
#define E 4096
#define M 16
#define LN_EPS 1e-5f

// ---------------------------------------------------------------------------
// Kernel 1: L2-normalize each joint row, scale by sqrt(E)=64, write to d_out.
// ---------------------------------------------------------------------------
__global__ void norm17_kernel(const float* __restrict__ je, float* __restrict__ out) {
    const int row = blockIdx.x;
    const float* __restrict__ src = je + (size_t)row * E;
    float* __restrict__ dst = out + (size_t)row * E;

    float ss = 0.0f;
    // 4096 floats / 256 threads = 16 per thread = 4 float4
    float4 v[4];
    #pragma unroll
    for (int i = 0; i < 4; ++i) {
        int idx = threadIdx.x + i * 256;          // float4 index
        v[i] = ((const float4*)src)[idx];
        ss += v[i].x * v[i].x + v[i].y * v[i].y + v[i].z * v[i].z + v[i].w * v[i].w;
    }
    // block reduce (4 waves of 64)
    for (int off = 32; off; off >>= 1) ss += __shfl_down(ss, off, 64);
    __shared__ float red[4];
    if ((threadIdx.x & 63) == 0) red[threadIdx.x >> 6] = ss;
    __syncthreads();
    float total = red[0] + red[1] + red[2] + red[3];

    float scale = 64.0f / fmaxf(sqrtf(total), 1e-12f);
    #pragma unroll
    for (int i = 0; i < 4; ++i) {
        int idx = threadIdx.x + i * 256;
        float4 o = v[i];
        o.x *= scale; o.y *= scale; o.z *= scale; o.w *= scale;
        ((float4*)dst)[idx] = o;
    }
}

// ---------------------------------------------------------------------------
// Skinny GEMM: out[m][n] += sum_{k in chunk} x[m][k] * W[k][n]
// X (16 x KTOT) staged in LDS per K-chunk; optional gather build from
// joint embeddings + bone_pairs (k < E -> pair[0], else pair[1]).
// grid.x = KTOT/KC (k-chunks), grid.y = E/NCOLS (col tiles), 256 threads.
// Each thread owns 2 adjacent columns (float2 loads of W).
// Partial sums combined with atomicAdd (out must be pre-zeroed).
// ---------------------------------------------------------------------------
template <int KTOT, int KC, bool GATHER>
__global__ __launch_bounds__(256) void skinny_gemm_kernel(
        const float* __restrict__ X,        // [16][KTOT] (GATHER=false)
        const float* __restrict__ W,        // [KTOT][E]
        float* __restrict__ out,            // [16][E], pre-zeroed
        const int* __restrict__ pairs,      // [16][2]  (GATHER=true)
        const float* __restrict__ joint) {  // [J][E]   (GATHER=true)

    __shared__ float xs[M][KC];
    const int k0 = blockIdx.x * KC;

    // stage X chunk: 16*KC floats, as float4
    for (int s = threadIdx.x; s < M * KC / 4; s += 256) {
        const int m  = s / (KC / 4);
        const int k4 = s % (KC / 4);
        const float* srow;
        if (GATHER) {
            const int half = (k0 >= E) ? 1 : 0;
            const int j = pairs[2 * m + half];
            srow = joint + (size_t)j * E + (k0 & (E - 1));
        } else {
            srow = X + (size_t)m * KTOT + k0;
        }
        ((float4*)&xs[m][0])[k4] = ((const float4*)srow)[k4];
    }
    __syncthreads();

    const int col = blockIdx.y * 512 + threadIdx.x * 2;
    float2 acc[M];
    #pragma unroll
    for (int m = 0; m < M; ++m) { acc[m].x = 0.0f; acc[m].y = 0.0f; }

    const float* __restrict__ wp = W + (size_t)k0 * E + col;
    #pragma unroll 4
    for (int k = 0; k < KC; ++k) {
        const float2 w = *(const float2*)wp;
        wp += E;
        #pragma unroll
        for (int m = 0; m < M; ++m) {
            const float xv = xs[m][k];
            acc[m].x = fmaf(xv, w.x, acc[m].x);
            acc[m].y = fmaf(xv, w.y, acc[m].y);
        }
    }

    #pragma unroll
    for (int m = 0; m < M; ++m) {
        atomicAdd(&out[(size_t)m * E + col],     acc[m].x);
        atomicAdd(&out[(size_t)m * E + col + 1], acc[m].y);
    }
}

// ---------------------------------------------------------------------------
// Row LayerNorm: out[r] = LN(pre[r] + bias) * g + be, optional ReLU.
// One block per row (16 rows), 256 threads, row kept in registers.
// ---------------------------------------------------------------------------
__global__ void ln_row_kernel(const float* __restrict__ pre,
                              const float* __restrict__ bias,
                              const float* __restrict__ g,
                              const float* __restrict__ be,
                              float* __restrict__ out,
                              int relu) {
    const int r = blockIdx.x;
    const float* __restrict__ src = pre + (size_t)r * E;

    float4 v[4];
    float s = 0.0f, s2 = 0.0f;
    #pragma unroll
    for (int i = 0; i < 4; ++i) {
        int idx = threadIdx.x + i * 256;
        float4 p = ((const float4*)src)[idx];
        float4 b = ((const float4*)bias)[idx];
        p.x += b.x; p.y += b.y; p.z += b.z; p.w += b.w;
        v[i] = p;
        s  += p.x + p.y + p.z + p.w;
        s2 += p.x * p.x + p.y * p.y + p.z * p.z + p.w * p.w;
    }
    for (int off = 32; off; off >>= 1) {
        s  += __shfl_down(s,  off, 64);
        s2 += __shfl_down(s2, off, 64);
    }
    __shared__ float ra[4], rb[4];
    if ((threadIdx.x & 63) == 0) { ra[threadIdx.x >> 6] = s; rb[threadIdx.x >> 6] = s2; }
    __syncthreads();
    s  = ra[0] + ra[1] + ra[2] + ra[3];
    s2 = rb[0] + rb[1] + rb[2] + rb[3];

    const float mu  = s * (1.0f / E);
    const float var = s2 * (1.0f / E) - mu * mu;
    const float rs  = rsqrtf(var + LN_EPS);

    #pragma unroll
    for (int i = 0; i < 4; ++i) {
        int idx = threadIdx.x + i * 256;
        float4 gg = ((const float4*)g)[idx];
        float4 bb = ((const float4*)be)[idx];
        float4 o;
        o.x = (v[i].x - mu) * rs * gg.x + bb.x;
        o.y = (v[i].y - mu) * rs * gg.y + bb.y;
        o.z = (v[i].z - mu) * rs * gg.z + bb.z;
        o.w = (v[i].w - mu) * rs * gg.w + bb.w;
        if (relu) {
            o.x = fmaxf(o.x, 0.0f); o.y = fmaxf(o.y, 0.0f);
            o.z = fmaxf(o.z, 0.0f); o.w = fmaxf(o.w, 0.0f);
        }
        ((float4*)(out + (size_t)r * E))[idx] = o;
    }
}

// ---------------------------------------------------------------------------
extern "C" void kernel_launch(void* const* d_in, const int* in_sizes, int n_in,
                              void* d_out, int out_size, void* d_ws, size_t ws_size,
                              hipStream_t stream) {
    const float* je  = (const float*)d_in[0];
    const float* W1  = (const float*)d_in[1];
    const float* b1  = (const float*)d_in[2];
    const float* g1  = (const float*)d_in[3];
    const float* be1 = (const float*)d_in[4];
    const float* W2  = (const float*)d_in[5];
    const float* b2  = (const float*)d_in[6];
    const float* g2  = (const float*)d_in[7];
    const float* be2 = (const float*)d_in[8];
    const int*   bp  = (const int*)d_in[9];

    float* out       = (float*)d_out;
    float* joint_out = out;            // [17][4096]
    float* bone_out  = out + J * E;    // [16][4096]

    float* pre1 = (float*)d_ws;        // [16][4096]
    float* pre2 = pre1 + M * E;        // [16][4096]
    float* h    = pre2 + M * E;        // [16][4096]

    // zero the atomic accumulation buffers (ws is poisoned each call)
    hipMemsetAsync(d_ws, 0, 2 * (size_t)M * E * sizeof(float), stream);

    norm17_kernel<<<J, 256, 0, stream>>>(je, joint_out);

    // GEMM1: [16,8192] @ [8192,4096] ; 64 k-chunks x 8 col tiles = 512 blocks
    skinny_gemm_kernel<2 * E, 128, true><<<dim3(64, 8), 256, 0, stream>>>(
        nullptr, W1, pre1, bp, joint_out);

    ln_row_kernel<<<M, 256, 0, stream>>>(pre1, b1, g1, be1, h, 1);

    // GEMM2: [16,4096] @ [4096,4096] ; 32 k-chunks x 8 col tiles = 256 blocks
    skinny_gemm_kernel<E, 128, false><<<dim3(32, 8), 256, 0, stream>>>(
        h, W2, pre2, nullptr, nullptr);

    ln_row_kernel<<<M, 256, 0, stream>>>(pre2, b2, g2, be2, bone_out, 0);
}

// Round 3
// 277.753 us; speedup vs baseline: 1.1268x; 1.1268x over previous
//
#include <hip/hip_runtime.h>
#include <math.h>

#define J 17
#define E 4096
#define M 16
#define LN_EPS 1e-5f

// ---------------------------------------------------------------------------
// Kernel 1: L2-normalize each joint row, scale by sqrt(E)=64, write to d_out.
// ---------------------------------------------------------------------------
__global__ void norm17_kernel(const float* __restrict__ je, float* __restrict__ out) {
    const int row = blockIdx.x;
    const float* __restrict__ src = je + (size_t)row * E;
    float* __restrict__ dst = out + (size_t)row * E;

    float ss = 0.0f;
    float4 v[4];
    #pragma unroll
    for (int i = 0; i < 4; ++i) {
        int idx = threadIdx.x + i * 256;
        v[i] = ((const float4*)src)[idx];
        ss += v[i].x * v[i].x + v[i].y * v[i].y + v[i].z * v[i].z + v[i].w * v[i].w;
    }
    for (int off = 32; off; off >>= 1) ss += __shfl_down(ss, off, 64);
    __shared__ float red[4];
    if ((threadIdx.x & 63) == 0) red[threadIdx.x >> 6] = ss;
    __syncthreads();
    float total = red[0] + red[1] + red[2] + red[3];

    float scale = 64.0f / fmaxf(sqrtf(total), 1e-12f);
    #pragma unroll
    for (int i = 0; i < 4; ++i) {
        int idx = threadIdx.x + i * 256;
        float4 o = v[i];
        o.x *= scale; o.y *= scale; o.z *= scale; o.w *= scale;
        ((float4*)dst)[idx] = o;
    }
}

// ---------------------------------------------------------------------------
// Skinny GEMM, software-pipelined.
// Each block: one K-chunk (KC rows of W) x 1024-col tile. 256 threads,
// 4 cols/thread (float4 W loads). Two 4-row groups in flight (8 outstanding
// 16B loads/thread). X chunk staged in LDS (broadcast reads, ds_read_b128).
// PARTIAL=1: store per-chunk partials to part[chunk][M][E] (plain stores).
// PARTIAL=0: atomicAdd into pre (fallback if ws too small; pre pre-zeroed).
// ---------------------------------------------------------------------------
#define DO_GROUP(KB, W0, W1, W2, W3)                                  \
    {                                                                 \
        _Pragma("unroll")                                             \
        for (int m = 0; m < M; ++m) {                                 \
            const float4 xv = *(const float4*)&xs[m][(KB)];           \
            acc[m].x = fmaf(xv.x, W0.x, acc[m].x);                    \
            acc[m].x = fmaf(xv.y, W1.x, acc[m].x);                    \
            acc[m].x = fmaf(xv.z, W2.x, acc[m].x);                    \
            acc[m].x = fmaf(xv.w, W3.x, acc[m].x);                    \
            acc[m].y = fmaf(xv.x, W0.y, acc[m].y);                    \
            acc[m].y = fmaf(xv.y, W1.y, acc[m].y);                    \
            acc[m].y = fmaf(xv.z, W2.y, acc[m].y);                    \
            acc[m].y = fmaf(xv.w, W3.y, acc[m].y);                    \
            acc[m].z = fmaf(xv.x, W0.z, acc[m].z);                    \
            acc[m].z = fmaf(xv.y, W1.z, acc[m].z);                    \
            acc[m].z = fmaf(xv.z, W2.z, acc[m].z);                    \
            acc[m].z = fmaf(xv.w, W3.z, acc[m].z);                    \
            acc[m].w = fmaf(xv.x, W0.w, acc[m].w);                    \
            acc[m].w = fmaf(xv.y, W1.w, acc[m].w);                    \
            acc[m].w = fmaf(xv.z, W2.w, acc[m].w);                    \
            acc[m].w = fmaf(xv.w, W3.w, acc[m].w);                    \
        }                                                             \
    }

template <int KTOT, int KC, bool GATHER, bool PARTIAL>
__global__ __launch_bounds__(256) void gemm_kernel(
        const float* __restrict__ X,        // [M][KTOT] (GATHER=false)
        const float* __restrict__ W,        // [KTOT][E]
        float* __restrict__ part,           // [chunks][M][E] or pre[M][E]
        const int* __restrict__ pairs,      // [M][2]   (GATHER=true)
        const float* __restrict__ joint) {  // [J][E]   (GATHER=true)

    __shared__ float xs[M][KC];
    const int k0 = blockIdx.x * KC;

    for (int s = threadIdx.x; s < M * KC / 4; s += 256) {
        const int m  = s / (KC / 4);
        const int k4 = s % (KC / 4);
        const float* srow;
        if (GATHER) {
            const int half = (k0 >= E) ? 1 : 0;
            srow = joint + (size_t)pairs[2 * m + half] * E + (k0 & (E - 1));
        } else {
            srow = X + (size_t)m * KTOT + k0;
        }
        ((float4*)&xs[m][0])[k4] = ((const float4*)srow)[k4];
    }
    __syncthreads();

    const int col = blockIdx.y * 1024 + (threadIdx.x << 2);
    const float* __restrict__ wp = W + (size_t)k0 * E + col;

    float4 acc[M];
    #pragma unroll
    for (int m = 0; m < M; ++m) acc[m] = make_float4(0.f, 0.f, 0.f, 0.f);

    // prologue: two groups (8 W rows) in flight
    float4 wa0 = *(const float4*)(wp + (size_t)0 * E);
    float4 wa1 = *(const float4*)(wp + (size_t)1 * E);
    float4 wa2 = *(const float4*)(wp + (size_t)2 * E);
    float4 wa3 = *(const float4*)(wp + (size_t)3 * E);
    float4 wb0 = *(const float4*)(wp + (size_t)4 * E);
    float4 wb1 = *(const float4*)(wp + (size_t)5 * E);
    float4 wb2 = *(const float4*)(wp + (size_t)6 * E);
    float4 wb3 = *(const float4*)(wp + (size_t)7 * E);

    int kk = 0;
    for (; kk + 8 < KC; kk += 8) {
        DO_GROUP(kk, wa0, wa1, wa2, wa3);
        wa0 = *(const float4*)(wp + (size_t)(kk + 8)  * E);
        wa1 = *(const float4*)(wp + (size_t)(kk + 9)  * E);
        wa2 = *(const float4*)(wp + (size_t)(kk + 10) * E);
        wa3 = *(const float4*)(wp + (size_t)(kk + 11) * E);
        DO_GROUP(kk + 4, wb0, wb1, wb2, wb3);
        wb0 = *(const float4*)(wp + (size_t)(kk + 12) * E);
        wb1 = *(const float4*)(wp + (size_t)(kk + 13) * E);
        wb2 = *(const float4*)(wp + (size_t)(kk + 14) * E);
        wb3 = *(const float4*)(wp + (size_t)(kk + 15) * E);
    }
    DO_GROUP(kk,     wa0, wa1, wa2, wa3);
    DO_GROUP(kk + 4, wb0, wb1, wb2, wb3);

    if (PARTIAL) {
        float* dst = part + ((size_t)blockIdx.x * M) * E + col;
        #pragma unroll
        for (int m = 0; m < M; ++m) {
            *(float4*)(dst + (size_t)m * E) = acc[m];
        }
    } else {
        #pragma unroll
        for (int m = 0; m < M; ++m) {
            atomicAdd(&part[(size_t)m * E + col + 0], acc[m].x);
            atomicAdd(&part[(size_t)m * E + col + 1], acc[m].y);
            atomicAdd(&part[(size_t)m * E + col + 2], acc[m].z);
            atomicAdd(&part[(size_t)m * E + col + 3], acc[m].w);
        }
    }
}

// ---------------------------------------------------------------------------
// Reduce: pre[M][E] = sum over CHUNKS of part[ch][M][E].
// 256 blocks x 64 threads, one float4 per thread. Partials are L2/L3-hot.
// ---------------------------------------------------------------------------
template <int CHUNKS>
__global__ __launch_bounds__(64) void reduce_kernel(const float* __restrict__ part,
                                                    float* __restrict__ pre) {
    const size_t f = ((size_t)blockIdx.x * 64 + threadIdx.x) * 4;  // float index
    const float* p = part + f;
    float4 s0 = make_float4(0.f, 0.f, 0.f, 0.f);
    float4 s1 = s0, s2 = s0, s3 = s0;
    #pragma unroll
    for (int c = 0; c < CHUNKS; c += 4) {
        const float4 a = *(const float4*)(p + (size_t)(c + 0) * (M * E));
        const float4 b = *(const float4*)(p + (size_t)(c + 1) * (M * E));
        const float4 d = *(const float4*)(p + (size_t)(c + 2) * (M * E));
        const float4 e = *(const float4*)(p + (size_t)(c + 3) * (M * E));
        s0.x += a.x; s0.y += a.y; s0.z += a.z; s0.w += a.w;
        s1.x += b.x; s1.y += b.y; s1.z += b.z; s1.w += b.w;
        s2.x += d.x; s2.y += d.y; s2.z += d.z; s2.w += d.w;
        s3.x += e.x; s3.y += e.y; s3.z += e.z; s3.w += e.w;
    }
    float4 o;
    o.x = (s0.x + s1.x) + (s2.x + s3.x);
    o.y = (s0.y + s1.y) + (s2.y + s3.y);
    o.z = (s0.z + s1.z) + (s2.z + s3.z);
    o.w = (s0.w + s1.w) + (s2.w + s3.w);
    *(float4*)(pre + f) = o;
}

// ---------------------------------------------------------------------------
// Row LayerNorm: out[r] = LN(pre[r] + bias) * g + be, optional ReLU.
// ---------------------------------------------------------------------------
__global__ void ln_row_kernel(const float* __restrict__ pre,
                              const float* __restrict__ bias,
                              const float* __restrict__ g,
                              const float* __restrict__ be,
                              float* __restrict__ out,
                              int relu) {
    const int r = blockIdx.x;
    const float* __restrict__ src = pre + (size_t)r * E;

    float4 v[4];
    float s = 0.0f, s2 = 0.0f;
    #pragma unroll
    for (int i = 0; i < 4; ++i) {
        int idx = threadIdx.x + i * 256;
        float4 p = ((const float4*)src)[idx];
        float4 b = ((const float4*)bias)[idx];
        p.x += b.x; p.y += b.y; p.z += b.z; p.w += b.w;
        v[i] = p;
        s  += p.x + p.y + p.z + p.w;
        s2 += p.x * p.x + p.y * p.y + p.z * p.z + p.w * p.w;
    }
    for (int off = 32; off; off >>= 1) {
        s  += __shfl_down(s,  off, 64);
        s2 += __shfl_down(s2, off, 64);
    }
    __shared__ float ra[4], rb[4];
    if ((threadIdx.x & 63) == 0) { ra[threadIdx.x >> 6] = s; rb[threadIdx.x >> 6] = s2; }
    __syncthreads();
    s  = ra[0] + ra[1] + ra[2] + ra[3];
    s2 = rb[0] + rb[1] + rb[2] + rb[3];

    const float mu  = s * (1.0f / E);
    const float var = s2 * (1.0f / E) - mu * mu;
    const float rs  = rsqrtf(var + LN_EPS);

    #pragma unroll
    for (int i = 0; i < 4; ++i) {
        int idx = threadIdx.x + i * 256;
        float4 gg = ((const float4*)g)[idx];
        float4 bb = ((const float4*)be)[idx];
        float4 o;
        o.x = (v[i].x - mu) * rs * gg.x + bb.x;
        o.y = (v[i].y - mu) * rs * gg.y + bb.y;
        o.z = (v[i].z - mu) * rs * gg.z + bb.z;
        o.w = (v[i].w - mu) * rs * gg.w + bb.w;
        if (relu) {
            o.x = fmaxf(o.x, 0.0f); o.y = fmaxf(o.y, 0.0f);
            o.z = fmaxf(o.z, 0.0f); o.w = fmaxf(o.w, 0.0f);
        }
        ((float4*)(out + (size_t)r * E))[idx] = o;
    }
}

// ---------------------------------------------------------------------------
extern "C" void kernel_launch(void* const* d_in, const int* in_sizes, int n_in,
                              void* d_out, int out_size, void* d_ws, size_t ws_size,
                              hipStream_t stream) {
    const float* je  = (const float*)d_in[0];
    const float* W1  = (const float*)d_in[1];
    const float* b1  = (const float*)d_in[2];
    const float* g1  = (const float*)d_in[3];
    const float* be1 = (const float*)d_in[4];
    const float* W2  = (const float*)d_in[5];
    const float* b2  = (const float*)d_in[6];
    const float* g2  = (const float*)d_in[7];
    const float* be2 = (const float*)d_in[8];
    const int*   bp  = (const int*)d_in[9];

    float* out       = (float*)d_out;
    float* joint_out = out;            // [17][4096]
    float* bone_out  = out + J * E;    // [16][4096]

    const size_t part_floats = (size_t)64 * M * E;           // 64 chunks
    const size_t need = (part_floats + 3 * (size_t)M * E) * sizeof(float);

    norm17_kernel<<<J, 256, 0, stream>>>(je, joint_out);

    if (ws_size >= need) {
        // split-K partials + reduce (no atomics, no memset)
        float* part = (float*)d_ws;
        float* pre1 = part + part_floats;
        float* pre2 = pre1 + (size_t)M * E;
        float* h    = pre2 + (size_t)M * E;

        // GEMM1: [16,8192] @ [8192,4096]; KC=128 -> 64 chunks x 4 col tiles
        gemm_kernel<2 * E, 128, true, true><<<dim3(64, 4), 256, 0, stream>>>(
            nullptr, W1, part, bp, joint_out);
        reduce_kernel<64><<<256, 64, 0, stream>>>(part, pre1);
        ln_row_kernel<<<M, 256, 0, stream>>>(pre1, b1, g1, be1, h, 1);

        // GEMM2: [16,4096] @ [4096,4096]; KC=64 -> 64 chunks x 4 col tiles
        gemm_kernel<E, 64, false, true><<<dim3(64, 4), 256, 0, stream>>>(
            h, W2, part, nullptr, nullptr);
        reduce_kernel<64><<<256, 64, 0, stream>>>(part, pre2);
        ln_row_kernel<<<M, 256, 0, stream>>>(pre2, b2, g2, be2, bone_out, 0);
    } else {
        // atomic fallback (small ws)
        float* pre1 = (float*)d_ws;
        float* pre2 = pre1 + (size_t)M * E;
        float* h    = pre2 + (size_t)M * E;
        hipMemsetAsync(d_ws, 0, 2 * (size_t)M * E * sizeof(float), stream);

        gemm_kernel<2 * E, 128, true, false><<<dim3(64, 4), 256, 0, stream>>>(
            nullptr, W1, pre1, bp, joint_out);
        ln_row_kernel<<<M, 256, 0, stream>>>(pre1, b1, g1, be1, h, 1);
        gemm_kernel<E, 64, false, false><<<dim3(64, 4), 256, 0, stream>>>(
            h, W2, pre2, nullptr, nullptr);
        ln_row_kernel<<<M, 256, 0, stream>>>(pre2, b2, g2, be2, bone_out, 0);
    }
}